// Round 5
// baseline (318.311 us; speedup 1.0000x reference)
//
#include <hip/hip_runtime.h>

#define A_TOT 33600
#define BSZ 16
#define NMAX 32
#define NCLS 80

// flat float32 output offsets (elements), in reference return order
#define LAB_OFF 0                    // (16,33600)
#define BOX_OFF 537600               // (16,33600,4)
#define SC_OFF  2688000              // (16,33600,80)
#define POS_OFF 45696000             // (16,33600)

// top-k decomposition: 21 waves per (b,g); each wave scans a 1600-anchor slice
#define WPG 21
#define SLICE 1600
#define CAND_PER_BG (WPG * 9)        // 189 u64 keys

__device__ __forceinline__ float iou_box(const float4 p, const float4 q) {
    float ltx = fmaxf(p.x, q.x), lty = fmaxf(p.y, q.y);
    float rbx = fminf(p.z, q.z), rby = fminf(p.w, q.w);
    float w = fmaxf(rbx - ltx, 0.0f), h = fmaxf(rby - lty, 0.0f);
    float inter = w * h;
    float ap = (p.z - p.x) * (p.w - p.y);
    float aq = (q.z - q.x) * (q.w - q.y);
    return inter / (ap + aq - inter + 1e-9f);
}

// argmax-IoU gt for anchor A4 over all 32 gt of image b (first-max tie-break).
__device__ __forceinline__ int resolve_owner(const float4 A4, const float4* __restrict__ gr) {
    float bestv = -1.0f; int bestg = 0;
    for (int g = 0; g < NMAX; ++g) {
        float v = iou_box(gr[g], A4);
        if (v > bestv) { bestv = v; bestg = g; }
    }
    return bestg;
}

// K1a: per (b,g,slice): wave-local top-9 by key=(fbits(dist)<<32)|idx, no barriers.
__global__ __launch_bounds__(256) void k_topk_part(const float4* __restrict__ anc,
        const float4* __restrict__ gtb, const float* __restrict__ mgt,
        unsigned long long* __restrict__ part) {
    const int w = blockIdx.x * 4 + (threadIdx.x >> 6);   // global wave id
    const int lane = threadIdx.x & 63;
    const int bg = w / WPG;
    const int wl = w - bg * WPG;
    const float4 G = gtb[bg];
    const float gcx = (G.x + G.z) * 0.5f, gcy = (G.y + G.w) * 0.5f;
    const float m = mgt[bg];
    const int base = wl * SLICE;
    unsigned long long keys[9];
#pragma unroll
    for (int j = 0; j < 9; ++j) keys[j] = ~0ull;
    for (int t = 0; t < SLICE / 64; ++t) {
        const int i = base + lane + t * 64;
        const float4 a4 = anc[i];
        const float acx = (a4.x + a4.z) * 0.5f, acy = (a4.y + a4.w) * 0.5f;
        const float dx = gcx - acx, dy = gcy - acy;
        const float nd = sqrtf(dx * dx + dy * dy) * m;
        unsigned long long nk = ((unsigned long long)__float_as_uint(nd) << 32)
                              | (unsigned int)i;
        if (nk < keys[8]) {
#pragma unroll
            for (int j = 0; j < 9; ++j) {
                if (nk < keys[j]) {
                    unsigned long long t2 = keys[j]; keys[j] = nk; nk = t2;
                }
            }
        }
    }
    unsigned long long* dst = part + (size_t)w * 9;
    for (int k = 0; k < 9; ++k) {
        unsigned long long mn = keys[0];
#pragma unroll
        for (int off = 1; off < 64; off <<= 1) {
            unsigned long long o = __shfl_xor(mn, off);
            if (o < mn) mn = o;
        }
        if (lane == k) dst[k] = mn;
        if (keys[0] == mn) {
#pragma unroll
            for (int j = 0; j < 8; ++j) keys[j] = keys[j + 1];
            keys[8] = ~0ull;
        }
    }
}

// K1b: per (b,g,level): merge the per-slice candidates -> final top-9, atomicOr bit g.
__global__ __launch_bounds__(256) void k_topk_merge(const unsigned long long* __restrict__ part,
        unsigned int* __restrict__ mask) {
    const int w = blockIdx.x * 4 + (threadIdx.x >> 6);   // (bg, level) pair id
    if (w >= BSZ * NMAX * 3) return;
    const int lane = threadIdx.x & 63;
    const int bg = w / 3;
    const int lv = w - bg * 3;
    const int b = bg >> 5, g = bg & 31;
    const int cnt  = (lv == 0) ? 144 : (lv == 1) ? 36 : 9;
    const int coff = (lv == 0) ? 0   : (lv == 1) ? 144 : 180;
    const unsigned long long* src = part + (size_t)bg * CAND_PER_BG + coff;
    unsigned long long keys[3];
#pragma unroll
    for (int t = 0; t < 3; ++t) {
        const int i = lane + t * 64;
        unsigned long long nk = (i < cnt) ? src[i] : ~0ull;
#pragma unroll
        for (int j = 0; j <= t; ++j) {
            if (nk < keys[j] || j == t) {
                if (j == t) { keys[j] = nk; }
                else { unsigned long long t2 = keys[j]; keys[j] = nk; nk = t2; }
            }
        }
    }
    unsigned int* mrow = mask + (size_t)b * A_TOT;
    const unsigned int bitg = 1u << g;
    for (int k = 0; k < 9; ++k) {
        unsigned long long mn = keys[0];
#pragma unroll
        for (int off = 1; off < 64; off <<= 1) {
            unsigned long long o = __shfl_xor(mn, off);
            if (o < mn) mn = o;
        }
        if (lane == k) atomicOr(mrow + (unsigned int)(mn & 0xffffffffu), bitg);
        if (keys[0] == mn) {
            keys[0] = keys[1]; keys[1] = keys[2]; keys[2] = ~0ull;
        }
    }
}

// K2: per (b,g) threshold from the RAW mask, resolving multi-anchors inline.
// thr = sum/count + sqrt((sum2 - sum^2/A)/(A-1)), double, deterministic.
__global__ __launch_bounds__(256) void k_thresh(const float4* __restrict__ anc,
        const float4* __restrict__ gtb, const unsigned int* __restrict__ mask,
        double* __restrict__ thr) {
    const int bg = blockIdx.x;
    const int b = bg >> 5, g = bg & 31;
    const unsigned int bitg = 1u << g;
    const uint4* mrow4 = (const uint4*)(mask + (size_t)b * A_TOT);
    const float4 G = gtb[bg];
    const float4* gr = gtb + b * NMAX;
    double s = 0.0, s2 = 0.0; int c = 0;
    for (int q = threadIdx.x; q < A_TOT / 4; q += 256) {
        const uint4 w4 = mrow4[q];
#pragma unroll
        for (int j = 0; j < 4; ++j) {
            const unsigned int w = (j == 0) ? w4.x : (j == 1) ? w4.y : (j == 2) ? w4.z : w4.w;
            if (w) {
                const int a = q * 4 + j;
                bool owned;
                if (__popc(w) == 1) owned = (w == bitg);
                else owned = (resolve_owner(anc[a], gr) == g);
                if (owned) {
                    const float v = iou_box(G, anc[a]);
                    s += (double)v; s2 += (double)v * (double)v; ++c;
                }
            }
        }
    }
    const int lane = threadIdx.x & 63, wv = threadIdx.x >> 6;
#pragma unroll
    for (int off = 32; off > 0; off >>= 1) {
        s  += __shfl_down(s, off);
        s2 += __shfl_down(s2, off);
        c  += __shfl_down(c, off);
    }
    __shared__ double ss[4], ss2[4];
    __shared__ int sc[4];
    if (lane == 0) { ss[wv] = s; ss2[wv] = s2; sc[wv] = c; }
    __syncthreads();
    if (threadIdx.x == 0) {
        double S = ss[0] + ss[1] + ss[2] + ss[3];
        double S2 = ss2[0] + ss2[1] + ss2[2] + ss2[3];
        int C = sc[0] + sc[1] + sc[2] + sc[3];
        double t;
        if (C == 0) t = 1e300;                 // reference: 0/0 -> NaN -> compare false
        else {
            double var = (S2 - S * S / (double)A_TOT) / (double)(A_TOT - 1);
            if (var < 0.0) var = 0.0;
            t = S / (double)C + sqrt(var);
        }
        thr[bg] = t;
    }
}

// K3: single writer of the ENTIRE output, resolving multi-anchors inline.
// Block owns 256 consecutive anchors; zero-fills its contiguous score chunk
// (coalesced float4), syncs, scatters its positives into its own chunk.
__global__ __launch_bounds__(256) void k_out(const float4* __restrict__ anc,
        const float4* __restrict__ gtb, const int* __restrict__ glab,
        const float* __restrict__ mgt, const float4* __restrict__ pd,
        const unsigned int* __restrict__ mask, const double* __restrict__ thr,
        float* __restrict__ out) {
    const int idx = blockIdx.x * 256 + threadIdx.x;   // grid exactly BSZ*A_TOT/256
    const int b = idx / A_TOT;
    const int a = idx - b * A_TOT;
    const unsigned int m = mask[idx];
    bool keep = false; int g = 0;
    if (m) {
        if (__popc(m) > 1) g = resolve_owner(anc[a], gtb + b * NMAX);
        else g = __ffs(m) - 1;
        const float v = iou_box(gtb[b * NMAX + g], anc[a]);
        keep = ((double)v > thr[b * NMAX + g]) && (mgt[b * NMAX + g] != 0.0f);
    }
    const int ag = keep ? g : 0;          // argmax of all-zero cid -> 0
    const int lab = keep ? glab[b * NMAX + ag] : NCLS;
    out[LAB_OFF + idx] = (float)lab;
    *(float4*)(out + BOX_OFF + (size_t)idx * 4) = gtb[b * NMAX + ag];
    out[POS_OFF + idx] = keep ? 1.0f : 0.0f;
    float mx = 0.0f;
    if (keep) {
        const float4 P = pd[idx];
        const float4* gr = gtb + b * NMAX;
        mx = -INFINITY;
        for (int g2 = 0; g2 < NMAX; ++g2) mx = fmaxf(mx, iou_box(P, gr[g2]));  // iou(pd, gt)
    }
    // zero this block's score chunk: 256 anchors * 80 f32 = 5120 float4, coalesced
    float4* sc4 = (float4*)(out + SC_OFF) + (size_t)blockIdx.x * 5120;
    const float4 z = make_float4(0.f, 0.f, 0.f, 0.f);
#pragma unroll
    for (int k = 0; k < 20; ++k) sc4[threadIdx.x + k * 256] = z;
    __syncthreads();                      // chunk zeroed before intra-block scatter
    if (keep) out[SC_OFF + (size_t)idx * NCLS + lab] = mx;
}

extern "C" void kernel_launch(void* const* d_in, const int* in_sizes, int n_in,
                              void* d_out, int out_size, void* d_ws, size_t ws_size,
                              hipStream_t stream) {
    const float4* anc = (const float4*)d_in[0];
    const int*    glab = (const int*)d_in[2];
    const float4* gtb  = (const float4*)d_in[3];
    const float*  mgt  = (const float*)d_in[4];
    const float4* pd   = (const float4*)d_in[5];
    float* out = (float*)d_out;

    // workspace layout
    unsigned int* mask = (unsigned int*)d_ws;                                // 2,150,400 B
    double* thr = (double*)((char*)d_ws + 2150400);                          //     4,096 B
    unsigned long long* part = (unsigned long long*)((char*)d_ws + 2154496); //   774,144 B

    hipMemsetAsync(mask, 0, (size_t)BSZ * A_TOT * 4, stream);   // only fill (2.15 MB)

    k_topk_part <<<BSZ * NMAX * WPG / 4, 256, 0, stream>>>(anc, gtb, mgt, part);
    k_topk_merge<<<BSZ * NMAX * 3 / 4, 256, 0, stream>>>(part, mask);
    k_thresh<<<BSZ * NMAX, 256, 0, stream>>>(anc, gtb, mask, thr);
    k_out   <<<BSZ * A_TOT / 256, 256, 0, stream>>>(anc, gtb, glab, mgt, pd, mask, thr, out);
}

// Round 8
// 318.304 us; speedup vs baseline: 1.0000x; 1.0000x over previous
//
#include <hip/hip_runtime.h>

#define A_TOT 33600
#define BSZ 16
#define NMAX 32
#define NCLS 80

// flat float32 output offsets (elements), in reference return order
#define LAB_OFF 0                    // (16,33600)
#define BOX_OFF 537600               // (16,33600,4)
#define SC_OFF  2688000              // (16,33600,80)
#define POS_OFF 45696000             // (16,33600)

// top-k decomposition: 21 waves per (b,g); each wave scans a 1600-anchor slice
#define WPG 21
#define SLICE 1600
#define CAND_PER_BG (WPG * 9)        // 189 u64 keys

__device__ __forceinline__ float iou_box(const float4 p, const float4 q) {
    float ltx = fmaxf(p.x, q.x), lty = fmaxf(p.y, q.y);
    float rbx = fminf(p.z, q.z), rby = fminf(p.w, q.w);
    float w = fmaxf(rbx - ltx, 0.0f), h = fmaxf(rby - lty, 0.0f);
    float inter = w * h;
    float ap = (p.z - p.x) * (p.w - p.y);
    float aq = (q.z - q.x) * (q.w - q.y);
    return inter / (ap + aq - inter + 1e-9f);
}

// argmax-IoU gt for anchor A4 over all 32 gt of image b (first-max tie-break).
// NOTE: reference reassigns multi anchors to the GLOBAL argmax gt — which may
// not be one of the gts that selected the anchor. Threshold candidates must
// therefore come from the full mask scan, not a per-g top-27 list (round-6 bug).
__device__ __forceinline__ int resolve_owner(const float4 A4, const float4* __restrict__ gr) {
    float bestv = -1.0f; int bestg = 0;
    for (int g = 0; g < NMAX; ++g) {
        float v = iou_box(gr[g], A4);
        if (v > bestv) { bestv = v; bestg = g; }
    }
    return bestg;
}

// K1a: per (b,g,slice): wave-local top-9 by key=(fbits(dist)<<32)|idx, no barriers.
__global__ __launch_bounds__(256) void k_topk_part(const float4* __restrict__ anc,
        const float4* __restrict__ gtb, const float* __restrict__ mgt,
        unsigned long long* __restrict__ part) {
    const int w = blockIdx.x * 4 + (threadIdx.x >> 6);   // global wave id
    const int lane = threadIdx.x & 63;
    const int bg = w / WPG;
    const int wl = w - bg * WPG;
    const float4 G = gtb[bg];
    const float gcx = (G.x + G.z) * 0.5f, gcy = (G.y + G.w) * 0.5f;
    const float m = mgt[bg];
    const int base = wl * SLICE;
    unsigned long long keys[9];
#pragma unroll
    for (int j = 0; j < 9; ++j) keys[j] = ~0ull;
    for (int t = 0; t < SLICE / 64; ++t) {
        const int i = base + lane + t * 64;
        const float4 a4 = anc[i];
        const float acx = (a4.x + a4.z) * 0.5f, acy = (a4.y + a4.w) * 0.5f;
        const float dx = gcx - acx, dy = gcy - acy;
        const float nd = sqrtf(dx * dx + dy * dy) * m;
        unsigned long long nk = ((unsigned long long)__float_as_uint(nd) << 32)
                              | (unsigned int)i;
        if (nk < keys[8]) {
#pragma unroll
            for (int j = 0; j < 9; ++j) {
                if (nk < keys[j]) {
                    unsigned long long t2 = keys[j]; keys[j] = nk; nk = t2;
                }
            }
        }
    }
    unsigned long long* dst = part + (size_t)w * 9;
    for (int k = 0; k < 9; ++k) {
        unsigned long long mn = keys[0];
#pragma unroll
        for (int off = 1; off < 64; off <<= 1) {
            unsigned long long o = __shfl_xor(mn, off);
            if (o < mn) mn = o;
        }
        if (lane == k) dst[k] = mn;
        if (keys[0] == mn) {
#pragma unroll
            for (int j = 0; j < 8; ++j) keys[j] = keys[j + 1];
            keys[8] = ~0ull;
        }
    }
}

// K1b: per (b,g,level): merge the per-slice candidates -> final top-9, atomicOr bit g.
__global__ __launch_bounds__(256) void k_topk_merge(const unsigned long long* __restrict__ part,
        unsigned int* __restrict__ mask) {
    const int w = blockIdx.x * 4 + (threadIdx.x >> 6);   // (bg, level) pair id
    if (w >= BSZ * NMAX * 3) return;
    const int lane = threadIdx.x & 63;
    const int bg = w / 3;
    const int lv = w - bg * 3;
    const int b = bg >> 5, g = bg & 31;
    const int cnt  = (lv == 0) ? 144 : (lv == 1) ? 36 : 9;
    const int coff = (lv == 0) ? 0   : (lv == 1) ? 144 : 180;
    const unsigned long long* src = part + (size_t)bg * CAND_PER_BG + coff;
    unsigned long long keys[3];
#pragma unroll
    for (int t = 0; t < 3; ++t) {
        const int i = lane + t * 64;
        unsigned long long nk = (i < cnt) ? src[i] : ~0ull;
#pragma unroll
        for (int j = 0; j <= t; ++j) {
            if (nk < keys[j] || j == t) {
                if (j == t) { keys[j] = nk; }
                else { unsigned long long t2 = keys[j]; keys[j] = nk; nk = t2; }
            }
        }
    }
    unsigned int* mrow = mask + (size_t)b * A_TOT;
    const unsigned int bitg = 1u << g;
    for (int k = 0; k < 9; ++k) {
        unsigned long long mn = keys[0];
#pragma unroll
        for (int off = 1; off < 64; off <<= 1) {
            unsigned long long o = __shfl_xor(mn, off);
            if (o < mn) mn = o;
        }
        if (lane == k) atomicOr(mrow + (unsigned int)(mn & 0xffffffffu), bitg);
        if (keys[0] == mn) {
            keys[0] = keys[1]; keys[1] = keys[2]; keys[2] = ~0ull;
        }
    }
}

// K2: per (b,g) threshold from the RAW mask, resolving multi-anchors inline.
// thr = sum/count + sqrt((sum2 - sum^2/A)/(A-1)), double, deterministic.
__global__ __launch_bounds__(256) void k_thresh(const float4* __restrict__ anc,
        const float4* __restrict__ gtb, const unsigned int* __restrict__ mask,
        double* __restrict__ thr) {
    const int bg = blockIdx.x;
    const int b = bg >> 5, g = bg & 31;
    const unsigned int bitg = 1u << g;
    const uint4* mrow4 = (const uint4*)(mask + (size_t)b * A_TOT);
    const float4 G = gtb[bg];
    const float4* gr = gtb + b * NMAX;
    double s = 0.0, s2 = 0.0; int c = 0;
    for (int q = threadIdx.x; q < A_TOT / 4; q += 256) {
        const uint4 w4 = mrow4[q];
#pragma unroll
        for (int j = 0; j < 4; ++j) {
            const unsigned int w = (j == 0) ? w4.x : (j == 1) ? w4.y : (j == 2) ? w4.z : w4.w;
            if (w) {
                const int a = q * 4 + j;
                bool owned;
                if (__popc(w) == 1) owned = (w == bitg);
                else owned = (resolve_owner(anc[a], gr) == g);
                if (owned) {
                    const float v = iou_box(G, anc[a]);
                    s += (double)v; s2 += (double)v * (double)v; ++c;
                }
            }
        }
    }
    const int lane = threadIdx.x & 63, wv = threadIdx.x >> 6;
#pragma unroll
    for (int off = 32; off > 0; off >>= 1) {
        s  += __shfl_down(s, off);
        s2 += __shfl_down(s2, off);
        c  += __shfl_down(c, off);
    }
    __shared__ double ss[4], ss2[4];
    __shared__ int sc[4];
    if (lane == 0) { ss[wv] = s; ss2[wv] = s2; sc[wv] = c; }
    __syncthreads();
    if (threadIdx.x == 0) {
        double S = ss[0] + ss[1] + ss[2] + ss[3];
        double S2 = ss2[0] + ss2[1] + ss2[2] + ss2[3];
        int C = sc[0] + sc[1] + sc[2] + sc[3];
        double t;
        if (C == 0) t = 1e300;                 // reference: 0/0 -> NaN -> compare false
        else {
            double var = (S2 - S * S / (double)A_TOT) / (double)(A_TOT - 1);
            if (var < 0.0) var = 0.0;
            t = S / (double)C + sqrt(var);
        }
        thr[bg] = t;
    }
}

// K3: single writer of the ENTIRE output, resolving multi-anchors inline.
// Block owns 256 consecutive anchors; zero-fills its contiguous score chunk
// (coalesced float4), syncs, scatters its positives into its own chunk.
__global__ __launch_bounds__(256) void k_out(const float4* __restrict__ anc,
        const float4* __restrict__ gtb, const int* __restrict__ glab,
        const float* __restrict__ mgt, const float4* __restrict__ pd,
        const unsigned int* __restrict__ mask, const double* __restrict__ thr,
        float* __restrict__ out) {
    const int idx = blockIdx.x * 256 + threadIdx.x;   // grid exactly BSZ*A_TOT/256
    const int b = idx / A_TOT;
    const int a = idx - b * A_TOT;
    const unsigned int m = mask[idx];
    bool keep = false; int g = 0;
    if (m) {
        if (__popc(m) > 1) g = resolve_owner(anc[a], gtb + b * NMAX);
        else g = __ffs(m) - 1;
        const float v = iou_box(gtb[b * NMAX + g], anc[a]);
        keep = ((double)v > thr[b * NMAX + g]) && (mgt[b * NMAX + g] != 0.0f);
    }
    const int ag = keep ? g : 0;          // argmax of all-zero cid -> 0
    const int lab = keep ? glab[b * NMAX + ag] : NCLS;
    out[LAB_OFF + idx] = (float)lab;
    *(float4*)(out + BOX_OFF + (size_t)idx * 4) = gtb[b * NMAX + ag];
    out[POS_OFF + idx] = keep ? 1.0f : 0.0f;
    float mx = 0.0f;
    if (keep) {
        const float4 P = pd[idx];
        const float4* gr = gtb + b * NMAX;
        mx = -INFINITY;
        for (int g2 = 0; g2 < NMAX; ++g2) mx = fmaxf(mx, iou_box(P, gr[g2]));  // iou(pd, gt)
    }
    // zero this block's score chunk: 256 anchors * 80 f32 = 5120 float4, coalesced
    float4* sc4 = (float4*)(out + SC_OFF) + (size_t)blockIdx.x * 5120;
    const float4 z = make_float4(0.f, 0.f, 0.f, 0.f);
#pragma unroll
    for (int k = 0; k < 20; ++k) sc4[threadIdx.x + k * 256] = z;
    __syncthreads();                      // chunk zeroed before intra-block scatter
    if (keep) out[SC_OFF + (size_t)idx * NCLS + lab] = mx;
}

extern "C" void kernel_launch(void* const* d_in, const int* in_sizes, int n_in,
                              void* d_out, int out_size, void* d_ws, size_t ws_size,
                              hipStream_t stream) {
    const float4* anc = (const float4*)d_in[0];
    const int*    glab = (const int*)d_in[2];
    const float4* gtb  = (const float4*)d_in[3];
    const float*  mgt  = (const float*)d_in[4];
    const float4* pd   = (const float4*)d_in[5];
    float* out = (float*)d_out;

    // workspace layout
    unsigned int* mask = (unsigned int*)d_ws;                                // 2,150,400 B
    double* thr = (double*)((char*)d_ws + 2150400);                          //     4,096 B
    unsigned long long* part = (unsigned long long*)((char*)d_ws + 2154496); //   774,144 B

    hipMemsetAsync(mask, 0, (size_t)BSZ * A_TOT * 4, stream);   // only fill (2.15 MB)

    k_topk_part <<<BSZ * NMAX * WPG / 4, 256, 0, stream>>>(anc, gtb, mgt, part);
    k_topk_merge<<<BSZ * NMAX * 3 / 4, 256, 0, stream>>>(part, mask);
    k_thresh    <<<BSZ * NMAX, 256, 0, stream>>>(anc, gtb, mask, thr);
    k_out       <<<BSZ * A_TOT / 256, 256, 0, stream>>>(anc, gtb, glab, mgt, pd, mask, thr, out);
}